// Round 14
// baseline (1794.822 us; speedup 1.0000x reference)
//
#include <hip/hip_runtime.h>

// ---------------------------------------------------------------- types/helpers
typedef __bf16 bf16x8 __attribute__((ext_vector_type(8)));
typedef float  f32x4  __attribute__((ext_vector_type(4)));
typedef unsigned uint32x4 __attribute__((ext_vector_type(4)));

#define DEV __device__ __forceinline__

DEV ushort f2bf(float f) {                       // fp32 -> bf16 RNE
  unsigned u = __builtin_bit_cast(unsigned, f);
  u += 0x7FFFu + ((u >> 16) & 1u);
  return (ushort)(u >> 16);
}
DEV float bf2f(ushort u) { return __builtin_bit_cast(float, ((unsigned)u) << 16); }
DEV unsigned pk2(ushort a, ushort b) { return (unsigned)a | ((unsigned)b << 16); }

DEV f32x4 mfma16(bf16x8 a, bf16x8 b, f32x4 c) {
  return __builtin_amdgcn_mfma_f32_16x16x32_bf16(a, b, c, 0, 0, 0);
}

// jax.nn.gelu approximate=True: 0.5x(1+tanh(u)) == x*sigmoid(2u), one v_exp + rcp
DEV float gelu_f(float x) {
  float u = 0.7978845608028654f * (x + 0.044715f * x * x * x);
  return x / (1.f + __expf(-2.f * u));
}

#define SEQ  1024
#define NBAT 4
#define CDIM 256
#define EDIM 512
#define NLAY 6
#define NHEAD 8
#define HDIM 32
#define IDIM 1024
#define NVOC 50304
#define NROWS (NBAT * SEQ)   // 4096

// ---------------------------------------------------------------- embed gather + LN (E=512)
__global__ __launch_bounds__(64) void embed_ln_k(const int* __restrict__ ids,
                                                 const float* __restrict__ ew,
                                                 const float* __restrict__ w,
                                                 const float* __restrict__ b,
                                                 ushort* __restrict__ tok) {
  int m = blockIdx.x, t = threadIdx.x;
  const float* row = ew + (size_t)ids[m] * EDIM;
  float4 v0 = *(const float4*)(row + t * 8);
  float4 v1 = *(const float4*)(row + t * 8 + 4);
  float sm = v0.x + v0.y + v0.z + v0.w + v1.x + v1.y + v1.z + v1.w;
  float sq = v0.x*v0.x + v0.y*v0.y + v0.z*v0.z + v0.w*v0.w
           + v1.x*v1.x + v1.y*v1.y + v1.z*v1.z + v1.w*v1.w;
#pragma unroll
  for (int msk = 1; msk <= 32; msk <<= 1) { sm += __shfl_xor(sm, msk); sq += __shfl_xor(sq, msk); }
  float mean = sm * (1.f / EDIM);
  float var  = sq * (1.f / EDIM) - mean * mean;
  float inv  = rsqrtf(var + 1e-5f);
  float4 w0 = *(const float4*)(w + t * 8), w1 = *(const float4*)(w + t * 8 + 4);
  float4 b0 = *(const float4*)(b + t * 8), b1 = *(const float4*)(b + t * 8 + 4);
  ushort4 u0, u1;
  u0.x = f2bf((v0.x - mean) * inv * w0.x + b0.x);
  u0.y = f2bf((v0.y - mean) * inv * w0.y + b0.y);
  u0.z = f2bf((v0.z - mean) * inv * w0.z + b0.z);
  u0.w = f2bf((v0.w - mean) * inv * w0.w + b0.w);
  u1.x = f2bf((v1.x - mean) * inv * w1.x + b1.x);
  u1.y = f2bf((v1.y - mean) * inv * w1.y + b1.y);
  u1.z = f2bf((v1.z - mean) * inv * w1.z + b1.z);
  u1.w = f2bf((v1.w - mean) * inv * w1.w + b1.w);
  *(ushort4*)(tok + (size_t)m * EDIM + t * 8)     = u0;
  *(ushort4*)(tok + (size_t)m * EDIM + t * 8 + 4) = u1;
}

// ---------------------------------------------------------------- LayerNorm (C=256) -> bf16, wave-per-row
template <bool DUAL>
__global__ __launch_bounds__(256) void ln_k(const float* __restrict__ x,
                                            const float* __restrict__ w1, const float* __restrict__ b1,
                                            const float* __restrict__ w2, const float* __restrict__ b2,
                                            ushort* __restrict__ o1, ushort* __restrict__ o2) {
  int wave = threadIdx.x >> 6, t = threadIdx.x & 63;
  int m = blockIdx.x * 4 + wave;
  const float* row = x + (size_t)m * CDIM;
  float4 v = *(const float4*)(row + t * 4);
  float sm = v.x + v.y + v.z + v.w;
  float sq = v.x*v.x + v.y*v.y + v.z*v.z + v.w*v.w;
#pragma unroll
  for (int msk = 1; msk <= 32; msk <<= 1) { sm += __shfl_xor(sm, msk); sq += __shfl_xor(sq, msk); }
  float mean = sm * (1.f / CDIM);
  float var  = sq * (1.f / CDIM) - mean * mean;
  float inv  = rsqrtf(var + 1e-5f);
  float n0 = (v.x - mean) * inv, n1 = (v.y - mean) * inv, n2 = (v.z - mean) * inv, n3 = (v.w - mean) * inv;
  {
    float4 wv = *(const float4*)(w1 + t * 4), bv = *(const float4*)(b1 + t * 4);
    ushort4 u; u.x = f2bf(n0*wv.x+bv.x); u.y = f2bf(n1*wv.y+bv.y); u.z = f2bf(n2*wv.z+bv.z); u.w = f2bf(n3*wv.w+bv.w);
    *(ushort4*)(o1 + (size_t)m * CDIM + t * 4) = u;
  }
  if constexpr (DUAL) {
    float4 wv = *(const float4*)(w2 + t * 4), bv = *(const float4*)(b2 + t * 4);
    ushort4 u; u.x = f2bf(n0*wv.x+bv.x); u.y = f2bf(n1*wv.y+bv.y); u.z = f2bf(n2*wv.z+bv.z); u.w = f2bf(n3*wv.w+bv.w);
    *(ushort4*)(o2 + (size_t)m * CDIM + t * 4) = u;
  }
}

// ---------------------------------------------------------------- MFMA GEMM, 128x128 tile, K_STEP=64 (logits)
enum { GF_BIAS = 1, GF_GELU = 2, GF_ACC = 4, GF_BF16O = 8, GF_WF32 = 16 };

template <int FLAGS>
__global__ __launch_bounds__(256) void gemm_k(const ushort* __restrict__ A, int lda,
                                              const void* __restrict__ Wv, int ldw,
                                              const float* __restrict__ bias,
                                              void* __restrict__ C, int ldc, int K) {
  __shared__ __attribute__((aligned(16))) ushort lsA[128 * 64];
  __shared__ __attribute__((aligned(16))) ushort lsB[128 * 64];
  const int tid = threadIdx.x, lane = tid & 63, wave = tid >> 6;
  const int wm = wave >> 1, wn = wave & 1;
  const int row0 = blockIdx.x * 128, col0 = blockIdx.y * 128;
  const int l15 = lane & 15, koff = (lane >> 4) * 8;

  f32x4 acc[4][4] = {};
  for (int k0 = 0; k0 < K; k0 += 64) {
    __syncthreads();
#pragma unroll
    for (int p = 0; p < 4; ++p) {
      int c = tid + p * 256;          // 1024 chunks of 8 bf16
      int r = c >> 3, k8 = (c & 7) * 8;
      *(uint4*)(&lsA[c * 8]) = *(const uint4*)(A + (size_t)(row0 + r) * lda + k0 + k8);
      if constexpr (FLAGS & GF_WF32) {
        const float* gw = (const float*)Wv + (size_t)(col0 + r) * ldw + k0 + k8;
        float4 f0 = *(const float4*)gw, f1 = *(const float4*)(gw + 4);
        uint4 vw;
        vw.x = pk2(f2bf(f0.x), f2bf(f0.y)); vw.y = pk2(f2bf(f0.z), f2bf(f0.w));
        vw.z = pk2(f2bf(f1.x), f2bf(f1.y)); vw.w = pk2(f2bf(f1.z), f2bf(f1.w));
        *(uint4*)(&lsB[c * 8]) = vw;
      } else {
        *(uint4*)(&lsB[c * 8]) = *(const uint4*)((const ushort*)Wv + (size_t)(col0 + r) * ldw + k0 + k8);
      }
    }
    __syncthreads();
#pragma unroll
    for (int kk = 0; kk < 2; ++kk) {
      bf16x8 af[4], bfr[4];
#pragma unroll
      for (int mt = 0; mt < 4; ++mt)
        af[mt] = __builtin_bit_cast(bf16x8, *(const uint4*)(&lsA[(wm * 64 + mt * 16 + l15) * 64 + kk * 32 + koff]));
#pragma unroll
      for (int nt = 0; nt < 4; ++nt)
        bfr[nt] = __builtin_bit_cast(bf16x8, *(const uint4*)(&lsB[(wn * 64 + nt * 16 + l15) * 64 + kk * 32 + koff]));
#pragma unroll
      for (int mt = 0; mt < 4; ++mt)
#pragma unroll
        for (int nt = 0; nt < 4; ++nt)
          acc[mt][nt] = mfma16(af[mt], bfr[nt], acc[mt][nt]);
    }
  }
#pragma unroll
  for (int mt = 0; mt < 4; ++mt) {
#pragma unroll
    for (int nt = 0; nt < 4; ++nt) {
      int col = col0 + wn * 64 + nt * 16 + l15;
      float bv = (FLAGS & GF_BIAS) ? bias[col] : 0.f;
      int rowb = row0 + wm * 64 + mt * 16 + (lane >> 4) * 4;
#pragma unroll
      for (int r = 0; r < 4; ++r) {
        float v = acc[mt][nt][r] + bv;
        if constexpr (FLAGS & GF_GELU) v = gelu_f(v);
        size_t off = (size_t)(rowb + r) * ldc + col;
        if constexpr (FLAGS & GF_ACC)        ((float*)C)[off] += v;
        else if constexpr (FLAGS & GF_BF16O) ((ushort*)C)[off] = f2bf(v);
        else                                 ((float*)C)[off] = v;
      }
    }
  }
}

// ---------------------------------------------------------------- MFMA GEMM, 64x64 tile, K_STEP=64 (per-layer)
template <int FLAGS>
__global__ __launch_bounds__(256) void gemm64_k(const ushort* __restrict__ A, int lda,
                                                const void* __restrict__ Wv, int ldw,
                                                const float* __restrict__ bias,
                                                void* __restrict__ C, int ldc, int K) {
  __shared__ __attribute__((aligned(16))) ushort lsA[64 * 64];
  __shared__ __attribute__((aligned(16))) ushort lsB[64 * 64];
  const int tid = threadIdx.x, lane = tid & 63, wave = tid >> 6;
  const int row0 = blockIdx.x * 64, col0 = blockIdx.y * 64;
  const int l15 = lane & 15, lhi = lane >> 4, koff = lhi * 8;

  f32x4 acc[4] = {};
  for (int k0 = 0; k0 < K; k0 += 64) {
    __syncthreads();
#pragma unroll
    for (int p = 0; p < 2; ++p) {
      int c = tid + p * 256;          // 512 chunks of 8 bf16
      int r = c >> 3, k8 = (c & 7) * 8;
      *(uint4*)(&lsA[c * 8]) = *(const uint4*)(A + (size_t)(row0 + r) * lda + k0 + k8);
      if constexpr (FLAGS & GF_WF32) {
        const float* gw = (const float*)Wv + (size_t)(col0 + r) * ldw + k0 + k8;
        float4 f0 = *(const float4*)gw, f1 = *(const float4*)(gw + 4);
        uint4 vw;
        vw.x = pk2(f2bf(f0.x), f2bf(f0.y)); vw.y = pk2(f2bf(f0.z), f2bf(f0.w));
        vw.z = pk2(f2bf(f1.x), f2bf(f1.y)); vw.w = pk2(f2bf(f1.z), f2bf(f1.w));
        *(uint4*)(&lsB[c * 8]) = vw;
      } else {
        *(uint4*)(&lsB[c * 8]) = *(const uint4*)((const ushort*)Wv + (size_t)(col0 + r) * ldw + k0 + k8);
      }
    }
    __syncthreads();
#pragma unroll
    for (int kk = 0; kk < 2; ++kk) {
      bf16x8 af = __builtin_bit_cast(bf16x8, *(const uint4*)(&lsA[(wave * 16 + l15) * 64 + kk * 32 + koff]));
#pragma unroll
      for (int nt = 0; nt < 4; ++nt) {
        bf16x8 bfr = __builtin_bit_cast(bf16x8, *(const uint4*)(&lsB[(nt * 16 + l15) * 64 + kk * 32 + koff]));
        acc[nt] = mfma16(af, bfr, acc[nt]);
      }
    }
  }
#pragma unroll
  for (int nt = 0; nt < 4; ++nt) {
    int col = col0 + nt * 16 + l15;
    float bv = (FLAGS & GF_BIAS) ? bias[col] : 0.f;
    int rowb = row0 + wave * 16 + lhi * 4;
#pragma unroll
    for (int r = 0; r < 4; ++r) {
      float v = acc[nt][r] + bv;
      if constexpr (FLAGS & GF_GELU) v = gelu_f(v);
      size_t off = (size_t)(rowb + r) * ldc + col;
      if constexpr (FLAGS & GF_ACC)        ((float*)C)[off] += v;
      else if constexpr (FLAGS & GF_BF16O) ((ushort*)C)[off] = f2bf(v);
      else                                 ((float*)C)[off] = v;
    }
  }
}

// ---------------------------------------------------------------- fused QKV GEMM + bias + RoPE + scatter (bf16 W, K_STEP=64)
__global__ __launch_bounds__(256) void qkvrope_k(const ushort* __restrict__ A,
                                                 const ushort* __restrict__ W,
                                                 const float* __restrict__ bias,
                                                 ushort* __restrict__ Qo,
                                                 ushort* __restrict__ Ko,
                                                 ushort* __restrict__ Vt) {
  __shared__ __attribute__((aligned(16))) ushort lsA[64 * 64];
  __shared__ __attribute__((aligned(16))) ushort lsB[64 * 64];
  const int tid = threadIdx.x, lane = tid & 63, wave = tid >> 6;
  const int row0 = blockIdx.x * 64, col0 = blockIdx.y * 64;
  const int l15 = lane & 15, lhi = lane >> 4, koff = lhi * 8;

  f32x4 acc[4] = {};
  for (int k0 = 0; k0 < CDIM; k0 += 64) {
    __syncthreads();
#pragma unroll
    for (int p = 0; p < 2; ++p) {
      int c = tid + p * 256;
      int r = c >> 3, k8 = (c & 7) * 8;
      *(uint4*)(&lsA[c * 8]) = *(const uint4*)(A + (size_t)(row0 + r) * CDIM + k0 + k8);
      *(uint4*)(&lsB[c * 8]) = *(const uint4*)(W + (size_t)(col0 + r) * CDIM + k0 + k8);
    }
    __syncthreads();
#pragma unroll
    for (int kk = 0; kk < 2; ++kk) {
      bf16x8 af = __builtin_bit_cast(bf16x8, *(const uint4*)(&lsA[(wave * 16 + l15) * 64 + kk * 32 + koff]));
#pragma unroll
      for (int nt = 0; nt < 4; ++nt) {
        bf16x8 bfr = __builtin_bit_cast(bf16x8, *(const uint4*)(&lsB[(nt * 16 + l15) * 64 + kk * 32 + koff]));
        acc[nt] = mfma16(af, bfr, acc[nt]);
      }
    }
  }
  const int rowb = row0 + wave * 16 + lhi * 4;
  const int b = rowb >> 10, s0 = rowb & 1023;
#pragma unroll
  for (int nt = 0; nt < 4; ++nt) {
    int c = col0 + nt * 16 + l15;
    int which = c >> 8;                 // 0=q 1=k 2=v  (uniform per nt tile)
    int h = (c >> 5) & 7;
    int d = c & 31;
    size_t bh = (size_t)(b * NHEAD + h);
    float bv = bias[c];
    float val[4], part[4];
#pragma unroll
    for (int r = 0; r < 4; ++r) val[r] = acc[nt][r] + bv;
#pragma unroll
    for (int r = 0; r < 4; ++r) part[r] = __shfl_xor(val[r], 4);   // col c^4 (all lanes)
    if (d < 8 && which < 2) {
      float sgn = (d < 4) ? -1.f : 1.f;
      int j = d & 3;
      float invp = (j == 0) ? 1.f : (j == 1) ? 0.1f : (j == 2) ? 0.01f : 0.001f;
#pragma unroll
      for (int r = 0; r < 4; ++r) {
        float ang = (float)(s0 + r) * invp;
        float cs, sn;
        __sincosf(ang, &sn, &cs);
        val[r] = val[r] * cs + sgn * part[r] * sn;
      }
    }
    if (which == 2) {
      ushort4 u; u.x = f2bf(val[0]); u.y = f2bf(val[1]); u.z = f2bf(val[2]); u.w = f2bf(val[3]);
      *(ushort4*)(Vt + bh * HDIM * SEQ + (size_t)d * SEQ + s0) = u;
    } else {
      ushort* dst = (which == 0) ? Qo : Ko;
#pragma unroll
      for (int r = 0; r < 4; ++r)
        dst[(bh * SEQ + s0 + r) * HDIM + d] = f2bf(val[r]);
    }
  }
}

// ---------------------------------------------------------------- fused ao+fc2 accumulate GEMM (K = 256 + 1024, bf16 W, K_STEP=64)
__global__ __launch_bounds__(256) void gemm64_dual_k(const ushort* __restrict__ A1, int lda1,
                                                     const ushort* __restrict__ W1, int ldw1, int K1,
                                                     const ushort* __restrict__ A2, int lda2,
                                                     const ushort* __restrict__ W2, int ldw2, int K2,
                                                     const float* __restrict__ b1,
                                                     const float* __restrict__ b2,
                                                     float* __restrict__ C, int ldc) {
  __shared__ __attribute__((aligned(16))) ushort lsA[64 * 64];
  __shared__ __attribute__((aligned(16))) ushort lsB[64 * 64];
  const int tid = threadIdx.x, lane = tid & 63, wave = tid >> 6;
  const int row0 = blockIdx.x * 64, col0 = blockIdx.y * 64;
  const int l15 = lane & 15, lhi = lane >> 4, koff = lhi * 8;

  f32x4 acc[4] = {};
  for (int k0 = 0; k0 < K1 + K2; k0 += 64) {
    __syncthreads();
#pragma unroll
    for (int p = 0; p < 2; ++p) {
      int c = tid + p * 256;
      int r = c >> 3, k8 = (c & 7) * 8;
      const ushort* Ap; const ushort* Wp; int kk;
      if (k0 < K1) { Ap = A1 + (size_t)(row0 + r) * lda1; Wp = W1 + (size_t)(col0 + r) * ldw1; kk = k0 + k8; }
      else         { Ap = A2 + (size_t)(row0 + r) * lda2; Wp = W2 + (size_t)(col0 + r) * ldw2; kk = k0 - K1 + k8; }
      *(uint4*)(&lsA[c * 8]) = *(const uint4*)(Ap + kk);
      *(uint4*)(&lsB[c * 8]) = *(const uint4*)(Wp + kk);
    }
    __syncthreads();
#pragma unroll
    for (int kk = 0; kk < 2; ++kk) {
      bf16x8 af = __builtin_bit_cast(bf16x8, *(const uint4*)(&lsA[(wave * 16 + l15) * 64 + kk * 32 + koff]));
#pragma unroll
      for (int nt = 0; nt < 4; ++nt) {
        bf16x8 bfr = __builtin_bit_cast(bf16x8, *(const uint4*)(&lsB[(nt * 16 + l15) * 64 + kk * 32 + koff]));
        acc[nt] = mfma16(af, bfr, acc[nt]);
      }
    }
  }
#pragma unroll
  for (int nt = 0; nt < 4; ++nt) {
    int col = col0 + nt * 16 + l15;
    float bv = b1[col] + b2[col];
    int rowb = row0 + wave * 16 + lhi * 4;
#pragma unroll
    for (int r = 0; r < 4; ++r)
      C[(size_t)(rowb + r) * ldc + col] += acc[nt][r] + bv;
  }
}

// ---------------------------------------------------------------- fused: block 0 = sequential scan; blocks 1+ = weight fp32->bf16
DEV void cvt_range(const float* __restrict__ src, ushort* __restrict__ dst,
                   int n4, int idx, int stride) {
  for (int i = idx; i < n4; i += stride) {
    float4 f = ((const float4*)src)[i];
    ushort4 u; u.x = f2bf(f.x); u.y = f2bf(f.y); u.z = f2bf(f.z); u.w = f2bf(f.w);
    ((ushort4*)dst)[i] = u;
  }
}

__global__ __launch_bounds__(256, 1) void scan_fused_k(const float* __restrict__ ctx_w,
                                                       const float* __restrict__ prev_ctx,
                                                       const float* __restrict__ P,
                                                       const float* __restrict__ cn_w,
                                                       const float* __restrict__ cn_b,
                                                       float* __restrict__ x,
                                                       const float* __restrict__ qkv_w,
                                                       const float* __restrict__ ao_w,
                                                       const float* __restrict__ fc1_w,
                                                       const float* __restrict__ fc2_w,
                                                       const float* __restrict__ out_w,
                                                       ushort* __restrict__ WQKV,
                                                       ushort* __restrict__ WAO,
                                                       ushort* __restrict__ WFC1,
                                                       ushort* __restrict__ WFC2,
                                                       ushort* __restrict__ WOUT) {
  if (blockIdx.x > 0) {
    const int idx = (blockIdx.x - 1) * 256 + threadIdx.x;
    const int stride = (gridDim.x - 1) * 256;
    cvt_range(qkv_w, WQKV, NLAY * 768 * CDIM / 4, idx, stride);
    cvt_range(ao_w,  WAO,  NLAY * CDIM * CDIM / 4, idx, stride);
    cvt_range(fc1_w, WFC1, NLAY * IDIM * CDIM / 4, idx, stride);
    cvt_range(fc2_w, WFC2, NLAY * CDIM * IDIM / 4, idx, stride);
    cvt_range(out_w, WOUT, NVOC * CDIM / 4, idx, stride);
    return;
  }

  __shared__ __attribute__((aligned(16))) ushort g_lds[2][4 * 288];    // [buf][batch][col] stride 288
  __shared__ __attribute__((aligned(16))) float  part_lds[2][4][4][2]; // [buf][batch][wave]{s,q}
  const int tid = threadIdx.x, lane = tid & 63, wave = tid >> 6;
  const int l15 = lane & 15, lhi = lane >> 4;
  const int bb = l15 & 3;                 // batch this lane epilogues
  const int ss = l15 >> 2;                // acc tile this lane consumes
  const int ccol = wave * 64 + ss * 16 + lhi * 4;   // 4 output cols this lane owns

  // ---- per-lane epilogue constants for own 4 cols
  float4 wv  = *(const float4*)(cn_w + ccol);
  float4 bvv = *(const float4*)(cn_b + ccol);
  float s1v[4] = {}, c1v[4] = {};
#pragma unroll 1
  for (int kk = 0; kk < CDIM; kk += 4) {
    float4 wk = *(const float4*)(cn_w + kk);
    float4 bk = *(const float4*)(cn_b + kk);
#pragma unroll
    for (int j = 0; j < 4; ++j) {
      float4 Wr = *(const float4*)(ctx_w + (size_t)(ccol + j) * 768 + kk);
      s1v[j] += Wr.x * wk.x + Wr.y * wk.y + Wr.z * wk.z + Wr.w * wk.w;
      c1v[j] += Wr.x * bk.x + Wr.y * bk.y + Wr.z * bk.z + Wr.w * bk.w;
    }
  }

  // ---- stage bf16(prev_ctx) into g_lds[0]
  {
    float4 c4 = *(const float4*)(prev_ctx + bb * CDIM + ccol);
    ushort4 u; u.x = f2bf(c4.x); u.y = f2bf(c4.y); u.z = f2bf(c4.z); u.w = f2bf(c4.w);
    *(ushort4*)&g_lds[0][bb * 288 + ccol] = u;
  }

  // ---- plain-W fragments for step 0
  uint32x4 wfu[4][8];
#pragma unroll
  for (int mt = 0; mt < 4; ++mt)
#pragma unroll
    for (int kt = 0; kt < 8; ++kt) {
      const float* s = ctx_w + (size_t)(wave * 64 + mt * 16 + l15) * 768 + kt * 32 + lhi * 8;
      float4 f0 = *(const float4*)s, f1 = *(const float4*)(s + 4);
      uint32x4 vw;
      vw.x = pk2(f2bf(f0.x), f2bf(f0.y)); vw.y = pk2(f2bf(f0.z), f2bf(f0.w));
      vw.z = pk2(f2bf(f1.x), f2bf(f1.y)); vw.w = pk2(f2bf(f1.z), f2bf(f1.w));
      wfu[mt][kt] = vw;
    }
  float4 pf = *(const float4*)(P + ((size_t)bb * SEQ + 0) * CDIM + ccol);
  __syncthreads();

  // ---- step 0: raw0 = W @ bf16(prev_ctx); g_0 = gelu(raw0 + P[0])
  float gr[4];
  {
    uint32x4 bfr[8];
#pragma unroll
    for (int kt = 0; kt < 8; ++kt)
      bfr[kt] = *(const uint32x4*)(&g_lds[0][bb * 288 + kt * 32 + lhi * 8]);
    f32x4 acc[4] = {};
#pragma unroll
    for (int mt = 0; mt < 4; ++mt)
#pragma unroll
      for (int kt = 0; kt < 8; ++kt)
        acc[mt] = mfma16(__builtin_bit_cast(bf16x8, wfu[mt][kt]),
                         __builtin_bit_cast(bf16x8, bfr[kt]), acc[mt]);
    f32x4 av = (ss == 0) ? acc[0] : (ss == 1) ? acc[1] : (ss == 2) ? acc[2] : acc[3];
    gr[0] = gelu_f(av[0] + pf.x); gr[1] = gelu_f(av[1] + pf.y);
    gr[2] = gelu_f(av[2] + pf.z); gr[3] = gelu_f(av[3] + pf.w);
  }

  // ---- swap fragments to W' = W_c * diag(cn_w)
#pragma unroll
  for (int mt = 0; mt < 4; ++mt)
#pragma unroll
    for (int kt = 0; kt < 8; ++kt) {
      int k = kt * 32 + lhi * 8;
      const float* s = ctx_w + (size_t)(wave * 64 + mt * 16 + l15) * 768 + k;
      float4 f0 = *(const float4*)s, f1 = *(const float4*)(s + 4);
      float4 w0 = *(const float4*)(cn_w + k), w1 = *(const float4*)(cn_w + k + 4);
      uint32x4 vw;
      vw.x = pk2(f2bf(f0.x * w0.x), f2bf(f0.y * w0.y));
      vw.y = pk2(f2bf(f0.z * w0.z), f2bf(f0.w * w0.w));
      vw.z = pk2(f2bf(f1.x * w1.x), f2bf(f1.y * w1.y));
      vw.w = pk2(f2bf(f1.z * w1.z), f2bf(f1.w * w1.w));
      wfu[mt][kt] = vw;
    }
#pragma unroll
  for (int mt = 0; mt < 4; ++mt)
#pragma unroll
    for (int kt = 0; kt < 8; ++kt)
      asm volatile("" : "+v"(wfu[mt][kt]));

  // ---- P prefetch slots: iter t uses slot (t+1)&3 (=P[t+1]), loads slot t&3 (=P[t+4])
  float4 ps0, ps1, ps2, ps3;
  ps1 = *(const float4*)(P + ((size_t)bb * SEQ + 1) * CDIM + ccol);
  ps2 = *(const float4*)(P + ((size_t)bb * SEQ + 2) * CDIM + ccol);
  ps3 = *(const float4*)(P + ((size_t)bb * SEQ + 3) * CDIM + ccol);
  ps0 = ps3;   // placeholder; overwritten at t=0
  __syncthreads();                         // everyone done reading g_lds[0] staging

  // ---- write g_0 (overwrites staging) + wave partials into buffer 0
  {
    ushort4 u; u.x = f2bf(gr[0]); u.y = f2bf(gr[1]); u.z = f2bf(gr[2]); u.w = f2bf(gr[3]);
    *(ushort4*)&g_lds[0][bb * 288 + ccol] = u;
    float lsm = gr[0] + gr[1] + gr[2] + gr[3];
    float lsq = gr[0]*gr[0] + gr[1]*gr[1] + gr[2]*gr[2] + gr[3]*gr[3];
    lsm += __shfl_xor(lsm, 4);  lsq += __shfl_xor(lsq, 4);
    lsm += __shfl_xor(lsm, 8);  lsq += __shfl_xor(lsq, 8);
    lsm += __shfl_xor(lsm, 16); lsq += __shfl_xor(lsq, 16);
    lsm += __shfl_xor(lsm, 32); lsq += __shfl_xor(lsq, 32);
    if (ss == 0 && lhi == 0) {
      part_lds[0][bb][wave][0] = lsm;
      part_lds[0][bb][wave][1] = lsq;
    }
  }
  __syncthreads();

#define SCAN_STEP(T, CUR, NXT, PUSE, PLOAD)                                          \
  {                                                                                  \
    int tp = ((T) + 4 < SEQ) ? (T) + 4 : SEQ - 1;                                    \
    PLOAD = *(const float4*)(P + ((size_t)bb * SEQ + tp) * CDIM + ccol);             \
    uint32x4 bfr[8];                                                                 \
    _Pragma("unroll")                                                                \
    for (int kt = 0; kt < 8; ++kt)                                                   \
      bfr[kt] = *(const uint32x4*)(&g_lds[CUR][bb * 288 + kt * 32 + lhi * 8]);       \
    const float4* pp = (const float4*)&part_lds[CUR][bb][0][0];                      \
    float4 qpa = pp[0], qpb = pp[1];                                                 \
    f32x4 accA[4] = {}, accB[4] = {};                                                \
    _Pragma("unroll")                                                                \
    for (int mt = 0; mt < 4; ++mt) {                                                 \
      accA[mt] = mfma16(__builtin_bit_cast(bf16x8, wfu[mt][0]), __builtin_bit_cast(bf16x8, bfr[0]), accA[mt]); \
      accB[mt] = mfma16(__builtin_bit_cast(bf16x8, wfu[mt][4]), __builtin_bit_cast(bf16x8, bfr[4]), accB[mt]); \
      accA[mt] = mfma16(__builtin_bit_cast(bf16x8, wfu[mt][1]), __builtin_bit_cast(bf16x8, bfr[1]), accA[mt]); \
      accB[mt] = mfma16(__builtin_bit_cast(bf16x8, wfu[mt][5]), __builtin_bit_cast(bf16x8, bfr[5]), accB[mt]); \
      accA[mt] = mfma16(__builtin_bit_cast(bf16x8, wfu[mt][2]), __builtin_bit_cast(bf16x8, bfr[2]), accA[mt]); \
      accB[mt] = mfma16(__builtin_bit_cast(bf16x8, wfu[mt][6]), __builtin_bit_cast(bf16x8, bfr[6]), accB[mt]); \
      accA[mt] = mfma16(__builtin_bit_cast(bf16x8, wfu[mt][3]), __builtin_bit_cast(bf16x8, bfr[3]), accA[mt]); \
      accB[mt] = mfma16(__builtin_bit_cast(bf16x8, wfu[mt][7]), __builtin_bit_cast(bf16x8, bfr[7]), accB[mt]); \
    }                                                                                \
    float sm = (qpa.x + qpa.z) + (qpb.x + qpb.z);                                    \
    float sq = (qpa.y + qpa.w) + (qpb.y + qpb.w);                                    \
    float mu  = sm * (1.f / CDIM);                                                   \
    float inv = rsqrtf(sq * (1.f / CDIM) - mu * mu + 1e-5f);                         \
    float invmu = inv * mu;                                                          \
    float4 y;                                                                        \
    y.x = wv.x * (inv * gr[0] - invmu) + bvv.x;                                      \
    y.y = wv.y * (inv * gr[1] - invmu) + bvv.y;                                      \
    y.z = wv.z * (inv * gr[2] - invmu) + bvv.z;                                      \
    y.w = wv.w * (inv * gr[3] - invmu) + bvv.w;                                      \
    *(float4*)(x + ((size_t)bb * SEQ + (T)) * CDIM + ccol) = y;                      \
    f32x4 avA = (ss == 0) ? accA[0] : (ss == 1) ? accA[1] : (ss == 2) ? accA[2] : accA[3]; \
    f32x4 avB = (ss == 0) ? accB[0] : (ss == 1) ? accB[1] : (ss == 2) ? accB[2] : accB[3]; \
    f32x4 av = avA + avB;                                                            \
    gr[0] = gelu_f(inv * av[0] - invmu * s1v[0] + c1v[0] + PUSE.x);                  \
    gr[1] = gelu_f(inv * av[1] - invmu * s1v[1] + c1v[1] + PUSE.y);                  \
    gr[2] = gelu_f(inv * av[2] - invmu * s1v[2] + c1v[2] + PUSE.z);                  \
    gr[3] = gelu_f(inv * av[3] - invmu * s1v[3] + c1v[3] + PUSE.w);                  \
    {                                                                                \
      ushort4 u; u.x = f2bf(gr[0]); u.y = f2bf(gr[1]); u.z = f2bf(gr[2]); u.w = f2bf(gr[3]); \
      *(ushort4*)&g_lds[NXT][bb * 288 + ccol] = u;                                   \
    }                                                                                \
    float lsm = gr[0] + gr[1] + gr[2] + gr[3];                                       \
    float lsq = gr[0]*gr[0] + gr[1]*gr[1] + gr[2]*gr[2] + gr[3]*gr[3];               \
    lsm += __shfl_xor(lsm, 4);  lsq += __shfl_xor(lsq, 4);                           \
    lsm += __shfl_xor(lsm, 8);  lsq += __shfl_xor(lsq, 8);                           \
    lsm += __shfl_xor(lsm, 16); lsq += __shfl_xor(lsq, 16);                          \
    lsm += __shfl_xor(lsm, 32); lsq += __shfl_xor(lsq, 32);                          \
    if (ss == 0 && lhi == 0) {                                                       \
      part_lds[NXT][bb][wave][0] = lsm;                                              \
      part_lds[NXT][bb][wave][1] = lsq;                                              \
    }                                                                                \
    asm volatile("s_waitcnt lgkmcnt(0)" ::: "memory");                               \
    __builtin_amdgcn_s_barrier();                                                    \
    __builtin_amdgcn_sched_barrier(0);                                               \
  }

  for (int t = 0; t < SEQ; t += 4) {
    SCAN_STEP(t,     0, 1, ps1, ps0)
    SCAN_STEP(t + 1, 1, 0, ps2, ps1)
    SCAN_STEP(t + 2, 0, 1, ps3, ps2)
    SCAN_STEP(t + 3, 1, 0, ps0, ps3)
  }
#undef SCAN_STEP
}

// ---------------------------------------------------------------- causal flash attention, D=32, MFMA
// No online max (|scores| << 80), deferred denominator reduce, 4 K-tiles
// (64 keys) per iteration for ILP. Balanced qtile = bx + 16*wave.
__global__ __launch_bounds__(256) void attn_k(const ushort* __restrict__ Q,
                                              const ushort* __restrict__ K,
                                              const ushort* __restrict__ VT,
                                              ushort* __restrict__ O) {
  __shared__ __attribute__((aligned(16))) ushort Plds[4 * 16 * 64];  // per-wave 16x64 P tile
  const int tid = threadIdx.x, lane = tid & 63, wave = tid >> 6;
  const int bh = blockIdx.y;
  const int qtile = blockIdx.x + 16 * wave;
  const int q0 = qtile * 16;
  const int l15 = lane & 15, lhi = lane >> 4;
  const float scale = 0.17677669529663689f;   // 1/sqrt(32)

  bf16x8 qa = __builtin_bit_cast(bf16x8,
      *(const uint4*)(Q + ((size_t)bh * SEQ + q0 + l15) * HDIM + lhi * 8));
  const ushort* Kb = K + (size_t)bh * SEQ * HDIM;
  const ushort* Vb = VT + (size_t)bh * HDIM * SEQ;
  ushort* Pw = &Plds[wave * 1024];

  f32x4 o0 = {}, o1 = {};
  float lacc[4] = {};

  for (int kt = 0; kt <= qtile; kt += 4) {
    f32x4 s[4];
    f32x4 z = {};
#pragma unroll
    for (int j = 0; j < 4; ++j) {
      bf16x8 kf = __builtin_bit_cast(bf16x8,
          *(const uint4*)(Kb + (size_t)((kt + j) * 16 + l15) * HDIM + lhi * 8));
      s[j] = mfma16(qa, kf, z);
    }
    float p[4][4];
#pragma unroll
    for (int j = 0; j < 4; ++j) {
      const bool tv = (kt + j <= qtile);
#pragma unroll
      for (int r = 0; r < 4; ++r) {
        int qr = q0 + lhi * 4 + r;
        int kc = (kt + j) * 16 + l15;
        p[j][r] = (tv && kc <= qr) ? __expf(s[j][r] * scale) : 0.f;
        lacc[r] += p[j][r];
      }
    }
#pragma unroll
    for (int j = 0; j < 4; ++j)
#pragma unroll
      for (int r = 0; r < 4; ++r)
        Pw[(lhi * 4 + r) * 64 + j * 16 + l15] = f2bf(p[j][r]);
#pragma unroll
    for (int w = 0; w < 2; ++w) {
      bf16x8 pa  = __builtin_bit_cast(bf16x8, *(const uint4*)(&Pw[l15 * 64 + w * 32 + lhi * 8]));
      bf16x8 v0f = __builtin_bit_cast(bf16x8,
          *(const uint4*)(Vb + (size_t)l15 * SEQ + kt * 16 + w * 32 + lhi * 8));
      bf16x8 v1f = __builtin_bit_cast(bf16x8,
          *(const uint4*)(Vb + (size_t)(16 + l15) * SEQ + kt * 16 + w * 32 + lhi * 8));
      o0 = mfma16(pa, v0f, o0);
      o1 = mfma16(pa, v1f, o1);
    }
  }
#pragma unroll
  for (int msk = 1; msk <= 8; msk <<= 1)
#pragma unroll
    for (int r = 0; r < 4; ++r) lacc[r] += __shfl_xor(lacc[r], msk);

  const int b = bh >> 3, h = bh & 7;
#pragma unroll
  for (int r = 0; r < 4; ++r) {
    float inv = 1.f / lacc[r];
    int qr = q0 + lhi * 4 + r;
    size_t base = ((size_t)(b * SEQ + qr)) * CDIM + h * HDIM;
    O[base + l15]      = f2bf(o0[r] * inv);
    O[base + 16 + l15] = f2bf(o1[r] * inv);
  }
}

// ---------------------------------------------------------------- launcher
static size_t ws_take(size_t& o, size_t bytes) {
  size_t r = o;
  o += (bytes + 255) & ~(size_t)255;
  return r;
}

extern "C" void kernel_launch(void* const* d_in, const int* in_sizes, int n_in,
                              void* d_out, int out_size, void* d_ws, size_t ws_size,
                              hipStream_t stream) {
  (void)in_sizes; (void)n_in; (void)out_size; (void)ws_size;
  const int*   input_ids = (const int*)  d_in[0];
  const float* prev_ctx  = (const float*)d_in[1];
  const float* embed_w   = (const float*)d_in[2];
  const float* en_w      = (const float*)d_in[3];
  const float* en_b      = (const float*)d_in[4];
  const float* ctx_w     = (const float*)d_in[5];
  const float* ctx_b     = (const float*)d_in[6];
  const float* cn_w      = (const float*)d_in[7];
  const float* cn_b      = (const float*)d_in[8];
  const float* ln1_w     = (const float*)d_in[9];
  const float* ln1_b     = (const float*)d_in[10];
  const float* ln2_w     = (const float*)d_in[11];
  const float* ln2_b     = (const float*)d_in[12];
  const float* qkv_w     = (const float*)d_in[13];
  const float* qkv_b     = (const float*)d_in[14];
  const float* ao_w      = (const float*)d_in[15];
  const float* ao_b      = (const float*)d_in[16];
  const float* fc1_w     = (const float*)d_in[17];
  const float* fc1_b     = (const float*)d_in[18];
  const float* fc2_w     = (const float*)d_in[19];
  const float* fc2_b     = (const float*)d_in[20];
  const float* fln_w     = (const float*)d_in[21];
  const float* fln_b     = (const float*)d_in[22];
  const float* out_w     = (const float*)d_in[23];
  float* logits = (float*)d_out;

  char* ws = (char*)d_ws;
  size_t o = 0;
  ushort* WB_OUT = (ushort*)(ws + ws_take(o, (size_t)NVOC * CDIM * 2));
  ushort* WQKV   = (ushort*)(ws + ws_take(o, (size_t)NLAY * 768 * CDIM * 2));
  ushort* WAO    = (ushort*)(ws + ws_take(o, (size_t)NLAY * CDIM * CDIM * 2));
  ushort* WFC1   = (ushort*)(ws + ws_take(o, (size_t)NLAY * IDIM * CDIM * 2));
  ushort* WFC2   = (ushort*)(ws + ws_take(o, (size_t)NLAY * CDIM * IDIM * 2));
  ushort* TOK    = (ushort*)(ws + ws_take(o, (size_t)NROWS * EDIM * 2));
  float*  PBUF   = (float*) (ws + ws_take(o, (size_t)NROWS * CDIM * 4));
  float*  XBUF   = (float*) (ws + ws_take(o, (size_t)NROWS * CDIM * 4));
  ushort* AIN    = (ushort*)(ws + ws_take(o, (size_t)NROWS * CDIM * 2));
  ushort* MIN    = (ushort*)(ws + ws_take(o, (size_t)NROWS * CDIM * 2));
  ushort* QB     = (ushort*)(ws + ws_take(o, (size_t)NROWS * CDIM * 2));
  ushort* KB     = (ushort*)(ws + ws_take(o, (size_t)NROWS * CDIM * 2));
  ushort* VTB    = (ushort*)(ws + ws_take(o, (size_t)NROWS * CDIM * 2));
  ushort* OB     = (ushort*)(ws + ws_take(o, (size_t)NROWS * CDIM * 2));
  ushort* TBUF   = (ushort*)(ws + ws_take(o, (size_t)NROWS * IDIM * 2));
  ushort* XLN    = (ushort*)(ws + ws_take(o, (size_t)NROWS * CDIM * 2));

  embed_ln_k<<<dim3(NROWS), dim3(64), 0, stream>>>(input_ids, embed_w, en_w, en_b, TOK);
  gemm64_k<GF_BIAS | GF_WF32><<<dim3(64, 4), dim3(256), 0, stream>>>(
      TOK, EDIM, (const void*)(ctx_w + 256), 768, ctx_b, (void*)PBUF, CDIM, EDIM);
  // block 0: sequential scan; blocks 1..256: all fp32->bf16 weight conversion (free)
  scan_fused_k<<<dim3(257), dim3(256), 0, stream>>>(
      ctx_w, prev_ctx, PBUF, cn_w, cn_b, XBUF,
      qkv_w, ao_w, fc1_w, fc2_w, out_w, WQKV, WAO, WFC1, WFC2, WB_OUT);

  for (int l = 0; l < NLAY; ++l) {
    ln_k<true><<<dim3(NROWS / 4), dim3(256), 0, stream>>>(
        XBUF, ln1_w + l * CDIM, ln1_b + l * CDIM, ln2_w + l * CDIM, ln2_b + l * CDIM, AIN, MIN);
    qkvrope_k<<<dim3(64, 12), dim3(256), 0, stream>>>(
        AIN, WQKV + (size_t)l * 768 * CDIM, qkv_b + l * 768, QB, KB, VTB);
    attn_k<<<dim3(16, 32), dim3(256), 0, stream>>>(QB, KB, VTB, OB);
    gemm64_k<GF_BIAS | GF_GELU | GF_BF16O><<<dim3(64, 16), dim3(256), 0, stream>>>(
        MIN, CDIM, (const void*)(WFC1 + (size_t)l * IDIM * CDIM), CDIM,
        fc1_b + l * IDIM, (void*)TBUF, IDIM, CDIM);
    gemm64_dual_k<<<dim3(64, 4), dim3(256), 0, stream>>>(
        OB, CDIM, WAO + (size_t)l * CDIM * CDIM, CDIM, CDIM,
        TBUF, IDIM, WFC2 + (size_t)l * CDIM * IDIM, IDIM, IDIM,
        ao_b + l * CDIM, fc2_b + l * CDIM, XBUF, CDIM);
  }

  ln_k<false><<<dim3(NROWS / 4), dim3(256), 0, stream>>>(
      XBUF, fln_w, fln_b, nullptr, nullptr, XLN, nullptr);
  gemm_k<0><<<dim3(32, 393), dim3(256), 0, stream>>>(
      XLN, CDIM, (const void*)WB_OUT, CDIM, nullptr, (void*)logits, NVOC, CDIM);
}

// Round 15
// 1680.367 us; speedup vs baseline: 1.0681x; 1.0681x over previous
//
#include <hip/hip_runtime.h>

// ---------------------------------------------------------------- types/helpers
typedef __bf16 bf16x8 __attribute__((ext_vector_type(8)));
typedef float  f32x4  __attribute__((ext_vector_type(4)));
typedef unsigned uint32x4 __attribute__((ext_vector_type(4)));

#define DEV __device__ __forceinline__

DEV ushort f2bf(float f) {                       // fp32 -> bf16 RNE
  unsigned u = __builtin_bit_cast(unsigned, f);
  u += 0x7FFFu + ((u >> 16) & 1u);
  return (ushort)(u >> 16);
}
DEV float bf2f(ushort u) { return __builtin_bit_cast(float, ((unsigned)u) << 16); }
DEV unsigned pk2(ushort a, ushort b) { return (unsigned)a | ((unsigned)b << 16); }

DEV f32x4 mfma16(bf16x8 a, bf16x8 b, f32x4 c) {
  return __builtin_amdgcn_mfma_f32_16x16x32_bf16(a, b, c, 0, 0, 0);
}

// jax.nn.gelu approximate=True: 0.5x(1+tanh(u)) == x*sigmoid(2u), one v_exp + rcp
DEV float gelu_f(float x) {
  float u = 0.7978845608028654f * (x + 0.044715f * x * x * x);
  return x / (1.f + __expf(-2.f * u));
}

#define SEQ  1024
#define NBAT 4
#define CDIM 256
#define EDIM 512
#define NLAY 6
#define NHEAD 8
#define HDIM 32
#define IDIM 1024
#define NVOC 50304
#define NROWS (NBAT * SEQ)   // 4096

// ---------------------------------------------------------------- embed gather + LN (E=512)
__global__ __launch_bounds__(64) void embed_ln_k(const int* __restrict__ ids,
                                                 const float* __restrict__ ew,
                                                 const float* __restrict__ w,
                                                 const float* __restrict__ b,
                                                 ushort* __restrict__ tok) {
  int m = blockIdx.x, t = threadIdx.x;
  const float* row = ew + (size_t)ids[m] * EDIM;
  float4 v0 = *(const float4*)(row + t * 8);
  float4 v1 = *(const float4*)(row + t * 8 + 4);
  float sm = v0.x + v0.y + v0.z + v0.w + v1.x + v1.y + v1.z + v1.w;
  float sq = v0.x*v0.x + v0.y*v0.y + v0.z*v0.z + v0.w*v0.w
           + v1.x*v1.x + v1.y*v1.y + v1.z*v1.z + v1.w*v1.w;
#pragma unroll
  for (int msk = 1; msk <= 32; msk <<= 1) { sm += __shfl_xor(sm, msk); sq += __shfl_xor(sq, msk); }
  float mean = sm * (1.f / EDIM);
  float var  = sq * (1.f / EDIM) - mean * mean;
  float inv  = rsqrtf(var + 1e-5f);
  float4 w0 = *(const float4*)(w + t * 8), w1 = *(const float4*)(w + t * 8 + 4);
  float4 b0 = *(const float4*)(b + t * 8), b1 = *(const float4*)(b + t * 8 + 4);
  ushort4 u0, u1;
  u0.x = f2bf((v0.x - mean) * inv * w0.x + b0.x);
  u0.y = f2bf((v0.y - mean) * inv * w0.y + b0.y);
  u0.z = f2bf((v0.z - mean) * inv * w0.z + b0.z);
  u0.w = f2bf((v0.w - mean) * inv * w0.w + b0.w);
  u1.x = f2bf((v1.x - mean) * inv * w1.x + b1.x);
  u1.y = f2bf((v1.y - mean) * inv * w1.y + b1.y);
  u1.z = f2bf((v1.z - mean) * inv * w1.z + b1.z);
  u1.w = f2bf((v1.w - mean) * inv * w1.w + b1.w);
  *(ushort4*)(tok + (size_t)m * EDIM + t * 8)     = u0;
  *(ushort4*)(tok + (size_t)m * EDIM + t * 8 + 4) = u1;
}

// ---------------------------------------------------------------- LayerNorm (C=256) -> bf16, wave-per-row
template <bool DUAL>
__global__ __launch_bounds__(256) void ln_k(const float* __restrict__ x,
                                            const float* __restrict__ w1, const float* __restrict__ b1,
                                            const float* __restrict__ w2, const float* __restrict__ b2,
                                            ushort* __restrict__ o1, ushort* __restrict__ o2) {
  int wave = threadIdx.x >> 6, t = threadIdx.x & 63;
  int m = blockIdx.x * 4 + wave;
  const float* row = x + (size_t)m * CDIM;
  float4 v = *(const float4*)(row + t * 4);
  float sm = v.x + v.y + v.z + v.w;
  float sq = v.x*v.x + v.y*v.y + v.z*v.z + v.w*v.w;
#pragma unroll
  for (int msk = 1; msk <= 32; msk <<= 1) { sm += __shfl_xor(sm, msk); sq += __shfl_xor(sq, msk); }
  float mean = sm * (1.f / CDIM);
  float var  = sq * (1.f / CDIM) - mean * mean;
  float inv  = rsqrtf(var + 1e-5f);
  float n0 = (v.x - mean) * inv, n1 = (v.y - mean) * inv, n2 = (v.z - mean) * inv, n3 = (v.w - mean) * inv;
  {
    float4 wv = *(const float4*)(w1 + t * 4), bv = *(const float4*)(b1 + t * 4);
    ushort4 u; u.x = f2bf(n0*wv.x+bv.x); u.y = f2bf(n1*wv.y+bv.y); u.z = f2bf(n2*wv.z+bv.z); u.w = f2bf(n3*wv.w+bv.w);
    *(ushort4*)(o1 + (size_t)m * CDIM + t * 4) = u;
  }
  if constexpr (DUAL) {
    float4 wv = *(const float4*)(w2 + t * 4), bv = *(const float4*)(b2 + t * 4);
    ushort4 u; u.x = f2bf(n0*wv.x+bv.x); u.y = f2bf(n1*wv.y+bv.y); u.z = f2bf(n2*wv.z+bv.z); u.w = f2bf(n3*wv.w+bv.w);
    *(ushort4*)(o2 + (size_t)m * CDIM + t * 4) = u;
  }
}

// ---------------------------------------------------------------- MFMA GEMM, 128x128 tile (logits)
enum { GF_BIAS = 1, GF_GELU = 2, GF_ACC = 4, GF_BF16O = 8, GF_WF32 = 16 };

template <int FLAGS>
__global__ __launch_bounds__(256) void gemm_k(const ushort* __restrict__ A, int lda,
                                              const void* __restrict__ Wv, int ldw,
                                              const float* __restrict__ bias,
                                              void* __restrict__ C, int ldc, int K) {
  __shared__ __attribute__((aligned(16))) ushort lsA[128 * 32];
  __shared__ __attribute__((aligned(16))) ushort lsB[128 * 32];
  const int tid = threadIdx.x, lane = tid & 63, wave = tid >> 6;
  const int wm = wave >> 1, wn = wave & 1;
  const int row0 = blockIdx.x * 128, col0 = blockIdx.y * 128;
  const int l15 = lane & 15, koff = (lane >> 4) * 8;

  f32x4 acc[4][4] = {};
  for (int k0 = 0; k0 < K; k0 += 32) {
    __syncthreads();
#pragma unroll
    for (int p = 0; p < 2; ++p) {
      int c = tid + p * 256;          // 512 chunks of 8 bf16
      int r = c >> 2, k8 = (c & 3) * 8;
      *(uint4*)(&lsA[c * 8]) = *(const uint4*)(A + (size_t)(row0 + r) * lda + k0 + k8);
      if constexpr (FLAGS & GF_WF32) {
        const float* gw = (const float*)Wv + (size_t)(col0 + r) * ldw + k0 + k8;
        float4 f0 = *(const float4*)gw, f1 = *(const float4*)(gw + 4);
        uint4 vw;
        vw.x = pk2(f2bf(f0.x), f2bf(f0.y)); vw.y = pk2(f2bf(f0.z), f2bf(f0.w));
        vw.z = pk2(f2bf(f1.x), f2bf(f1.y)); vw.w = pk2(f2bf(f1.z), f2bf(f1.w));
        *(uint4*)(&lsB[c * 8]) = vw;
      } else {
        *(uint4*)(&lsB[c * 8]) = *(const uint4*)((const ushort*)Wv + (size_t)(col0 + r) * ldw + k0 + k8);
      }
    }
    __syncthreads();
    bf16x8 af[4], bfr[4];
#pragma unroll
    for (int mt = 0; mt < 4; ++mt)
      af[mt] = __builtin_bit_cast(bf16x8, *(const uint4*)(&lsA[(wm * 64 + mt * 16 + l15) * 32 + koff]));
#pragma unroll
    for (int nt = 0; nt < 4; ++nt)
      bfr[nt] = __builtin_bit_cast(bf16x8, *(const uint4*)(&lsB[(wn * 64 + nt * 16 + l15) * 32 + koff]));
#pragma unroll
    for (int mt = 0; mt < 4; ++mt)
#pragma unroll
      for (int nt = 0; nt < 4; ++nt)
        acc[mt][nt] = mfma16(af[mt], bfr[nt], acc[mt][nt]);
  }
#pragma unroll
  for (int mt = 0; mt < 4; ++mt) {
#pragma unroll
    for (int nt = 0; nt < 4; ++nt) {
      int col = col0 + wn * 64 + nt * 16 + l15;
      float bv = (FLAGS & GF_BIAS) ? bias[col] : 0.f;
      int rowb = row0 + wm * 64 + mt * 16 + (lane >> 4) * 4;
#pragma unroll
      for (int r = 0; r < 4; ++r) {
        float v = acc[mt][nt][r] + bv;
        if constexpr (FLAGS & GF_GELU) v = gelu_f(v);
        size_t off = (size_t)(rowb + r) * ldc + col;
        if constexpr (FLAGS & GF_ACC)        ((float*)C)[off] += v;
        else if constexpr (FLAGS & GF_BF16O) ((ushort*)C)[off] = f2bf(v);
        else                                 ((float*)C)[off] = v;
      }
    }
  }
}

// ---------------------------------------------------------------- MFMA GEMM, 64x64 tile (per-layer)
template <int FLAGS>
__global__ __launch_bounds__(256) void gemm64_k(const ushort* __restrict__ A, int lda,
                                                const void* __restrict__ Wv, int ldw,
                                                const float* __restrict__ bias,
                                                void* __restrict__ C, int ldc, int K) {
  __shared__ __attribute__((aligned(16))) ushort lsA[64 * 32];
  __shared__ __attribute__((aligned(16))) ushort lsB[64 * 32];
  const int tid = threadIdx.x, lane = tid & 63, wave = tid >> 6;
  const int row0 = blockIdx.x * 64, col0 = blockIdx.y * 64;
  const int l15 = lane & 15, lhi = lane >> 4, koff = lhi * 8;

  f32x4 acc[4] = {};
  for (int k0 = 0; k0 < K; k0 += 32) {
    __syncthreads();
    {
      int r = tid >> 2, k8 = (tid & 3) * 8;
      *(uint4*)(&lsA[tid * 8]) = *(const uint4*)(A + (size_t)(row0 + r) * lda + k0 + k8);
      if constexpr (FLAGS & GF_WF32) {
        const float* gw = (const float*)Wv + (size_t)(col0 + r) * ldw + k0 + k8;
        float4 f0 = *(const float4*)gw, f1 = *(const float4*)(gw + 4);
        uint4 vw;
        vw.x = pk2(f2bf(f0.x), f2bf(f0.y)); vw.y = pk2(f2bf(f0.z), f2bf(f0.w));
        vw.z = pk2(f2bf(f1.x), f2bf(f1.y)); vw.w = pk2(f2bf(f1.z), f2bf(f1.w));
        *(uint4*)(&lsB[tid * 8]) = vw;
      } else {
        *(uint4*)(&lsB[tid * 8]) = *(const uint4*)((const ushort*)Wv + (size_t)(col0 + r) * ldw + k0 + k8);
      }
    }
    __syncthreads();
    bf16x8 af = __builtin_bit_cast(bf16x8, *(const uint4*)(&lsA[(wave * 16 + l15) * 32 + koff]));
#pragma unroll
    for (int nt = 0; nt < 4; ++nt) {
      bf16x8 bfr = __builtin_bit_cast(bf16x8, *(const uint4*)(&lsB[(nt * 16 + l15) * 32 + koff]));
      acc[nt] = mfma16(af, bfr, acc[nt]);
    }
  }
#pragma unroll
  for (int nt = 0; nt < 4; ++nt) {
    int col = col0 + nt * 16 + l15;
    float bv = (FLAGS & GF_BIAS) ? bias[col] : 0.f;
    int rowb = row0 + wave * 16 + lhi * 4;
#pragma unroll
    for (int r = 0; r < 4; ++r) {
      float v = acc[nt][r] + bv;
      if constexpr (FLAGS & GF_GELU) v = gelu_f(v);
      size_t off = (size_t)(rowb + r) * ldc + col;
      if constexpr (FLAGS & GF_ACC)        ((float*)C)[off] += v;
      else if constexpr (FLAGS & GF_BF16O) ((ushort*)C)[off] = f2bf(v);
      else                                 ((float*)C)[off] = v;
    }
  }
}

// ---------------------------------------------------------------- fused QKV GEMM + bias + RoPE + scatter (bf16 W)
__global__ __launch_bounds__(256) void qkvrope_k(const ushort* __restrict__ A,
                                                 const ushort* __restrict__ W,
                                                 const float* __restrict__ bias,
                                                 ushort* __restrict__ Qo,
                                                 ushort* __restrict__ Ko,
                                                 ushort* __restrict__ Vt) {
  __shared__ __attribute__((aligned(16))) ushort lsA[64 * 32];
  __shared__ __attribute__((aligned(16))) ushort lsB[64 * 32];
  const int tid = threadIdx.x, lane = tid & 63, wave = tid >> 6;
  const int row0 = blockIdx.x * 64, col0 = blockIdx.y * 64;
  const int l15 = lane & 15, lhi = lane >> 4, koff = lhi * 8;

  f32x4 acc[4] = {};
  for (int k0 = 0; k0 < CDIM; k0 += 32) {
    __syncthreads();
    {
      int r = tid >> 2, k8 = (tid & 3) * 8;
      *(uint4*)(&lsA[tid * 8]) = *(const uint4*)(A + (size_t)(row0 + r) * CDIM + k0 + k8);
      *(uint4*)(&lsB[tid * 8]) = *(const uint4*)(W + (size_t)(col0 + r) * CDIM + k0 + k8);
    }
    __syncthreads();
    bf16x8 af = __builtin_bit_cast(bf16x8, *(const uint4*)(&lsA[(wave * 16 + l15) * 32 + koff]));
#pragma unroll
    for (int nt = 0; nt < 4; ++nt) {
      bf16x8 bfr = __builtin_bit_cast(bf16x8, *(const uint4*)(&lsB[(nt * 16 + l15) * 32 + koff]));
      acc[nt] = mfma16(af, bfr, acc[nt]);
    }
  }
  const int rowb = row0 + wave * 16 + lhi * 4;
  const int b = rowb >> 10, s0 = rowb & 1023;
#pragma unroll
  for (int nt = 0; nt < 4; ++nt) {
    int c = col0 + nt * 16 + l15;
    int which = c >> 8;                 // 0=q 1=k 2=v  (uniform per nt tile)
    int h = (c >> 5) & 7;
    int d = c & 31;
    size_t bh = (size_t)(b * NHEAD + h);
    float bv = bias[c];
    float val[4], part[4];
#pragma unroll
    for (int r = 0; r < 4; ++r) val[r] = acc[nt][r] + bv;
#pragma unroll
    for (int r = 0; r < 4; ++r) part[r] = __shfl_xor(val[r], 4);   // col c^4 (all lanes)
    if (d < 8 && which < 2) {
      float sgn = (d < 4) ? -1.f : 1.f;
      int j = d & 3;
      float invp = (j == 0) ? 1.f : (j == 1) ? 0.1f : (j == 2) ? 0.01f : 0.001f;
#pragma unroll
      for (int r = 0; r < 4; ++r) {
        float ang = (float)(s0 + r) * invp;
        float cs, sn;
        __sincosf(ang, &sn, &cs);
        val[r] = val[r] * cs + sgn * part[r] * sn;
      }
    }
    if (which == 2) {
      ushort4 u; u.x = f2bf(val[0]); u.y = f2bf(val[1]); u.z = f2bf(val[2]); u.w = f2bf(val[3]);
      *(ushort4*)(Vt + bh * HDIM * SEQ + (size_t)d * SEQ + s0) = u;
    } else {
      ushort* dst = (which == 0) ? Qo : Ko;
#pragma unroll
      for (int r = 0; r < 4; ++r)
        dst[(bh * SEQ + s0 + r) * HDIM + d] = f2bf(val[r]);
    }
  }
}

// ---------------------------------------------------------------- fused ao+fc2 accumulate GEMM (K = 256 + 1024, bf16 W)
__global__ __launch_bounds__(256) void gemm64_dual_k(const ushort* __restrict__ A1, int lda1,
                                                     const ushort* __restrict__ W1, int ldw1, int K1,
                                                     const ushort* __restrict__ A2, int lda2,
                                                     const ushort* __restrict__ W2, int ldw2, int K2,
                                                     const float* __restrict__ b1,
                                                     const float* __restrict__ b2,
                                                     float* __restrict__ C, int ldc) {
  __shared__ __attribute__((aligned(16))) ushort lsA[64 * 32];
  __shared__ __attribute__((aligned(16))) ushort lsB[64 * 32];
  const int tid = threadIdx.x, lane = tid & 63, wave = tid >> 6;
  const int row0 = blockIdx.x * 64, col0 = blockIdx.y * 64;
  const int l15 = lane & 15, lhi = lane >> 4, koff = lhi * 8;

  f32x4 acc[4] = {};
  for (int k0 = 0; k0 < K1 + K2; k0 += 32) {
    __syncthreads();
    {
      int r = tid >> 2, k8 = (tid & 3) * 8;
      const ushort* Ap; const ushort* Wp; int kk;
      if (k0 < K1) { Ap = A1 + (size_t)(row0 + r) * lda1; Wp = W1 + (size_t)(col0 + r) * ldw1; kk = k0 + k8; }
      else         { Ap = A2 + (size_t)(row0 + r) * lda2; Wp = W2 + (size_t)(col0 + r) * ldw2; kk = k0 - K1 + k8; }
      *(uint4*)(&lsA[tid * 8]) = *(const uint4*)(Ap + kk);
      *(uint4*)(&lsB[tid * 8]) = *(const uint4*)(Wp + kk);
    }
    __syncthreads();
    bf16x8 af = __builtin_bit_cast(bf16x8, *(const uint4*)(&lsA[(wave * 16 + l15) * 32 + koff]));
#pragma unroll
    for (int nt = 0; nt < 4; ++nt) {
      bf16x8 bfr = __builtin_bit_cast(bf16x8, *(const uint4*)(&lsB[(nt * 16 + l15) * 32 + koff]));
      acc[nt] = mfma16(af, bfr, acc[nt]);
    }
  }
#pragma unroll
  for (int nt = 0; nt < 4; ++nt) {
    int col = col0 + nt * 16 + l15;
    float bv = b1[col] + b2[col];
    int rowb = row0 + wave * 16 + lhi * 4;
#pragma unroll
    for (int r = 0; r < 4; ++r)
      C[(size_t)(rowb + r) * ldc + col] += acc[nt][r] + bv;
  }
}

// ---------------------------------------------------------------- fused: block 0 = sequential scan; blocks 1+ = weight fp32->bf16
DEV void cvt_range(const float* __restrict__ src, ushort* __restrict__ dst,
                   int n4, int idx, int stride) {
  for (int i = idx; i < n4; i += stride) {
    float4 f = ((const float4*)src)[i];
    ushort4 u; u.x = f2bf(f.x); u.y = f2bf(f.y); u.z = f2bf(f.z); u.w = f2bf(f.w);
    ((ushort4*)dst)[i] = u;
  }
}

__global__ __launch_bounds__(256, 1) void scan_fused_k(const float* __restrict__ ctx_w,
                                                       const float* __restrict__ prev_ctx,
                                                       const float* __restrict__ P,
                                                       const float* __restrict__ cn_w,
                                                       const float* __restrict__ cn_b,
                                                       float* __restrict__ x,
                                                       const float* __restrict__ qkv_w,
                                                       const float* __restrict__ ao_w,
                                                       const float* __restrict__ fc1_w,
                                                       const float* __restrict__ fc2_w,
                                                       const float* __restrict__ out_w,
                                                       ushort* __restrict__ WQKV,
                                                       ushort* __restrict__ WAO,
                                                       ushort* __restrict__ WFC1,
                                                       ushort* __restrict__ WFC2,
                                                       ushort* __restrict__ WOUT) {
  if (blockIdx.x > 0) {
    const int idx = (blockIdx.x - 1) * 256 + threadIdx.x;
    const int stride = (gridDim.x - 1) * 256;
    cvt_range(qkv_w, WQKV, NLAY * 768 * CDIM / 4, idx, stride);
    cvt_range(ao_w,  WAO,  NLAY * CDIM * CDIM / 4, idx, stride);
    cvt_range(fc1_w, WFC1, NLAY * IDIM * CDIM / 4, idx, stride);
    cvt_range(fc2_w, WFC2, NLAY * CDIM * IDIM / 4, idx, stride);
    cvt_range(out_w, WOUT, NVOC * CDIM / 4, idx, stride);
    return;
  }

  __shared__ __attribute__((aligned(16))) ushort g_lds[2][4 * 288];    // [buf][batch][col] stride 288
  __shared__ __attribute__((aligned(16))) float  part_lds[2][4][4][2]; // [buf][batch][wave]{s,q}
  const int tid = threadIdx.x, lane = tid & 63, wave = tid >> 6;
  const int l15 = lane & 15, lhi = lane >> 4;
  const int bb = l15 & 3;                 // batch this lane epilogues
  const int ss = l15 >> 2;                // acc tile this lane consumes
  const int ccol = wave * 64 + ss * 16 + lhi * 4;   // 4 output cols this lane owns

  // ---- per-lane epilogue constants for own 4 cols
  float4 wv  = *(const float4*)(cn_w + ccol);
  float4 bvv = *(const float4*)(cn_b + ccol);
  float s1v[4] = {}, c1v[4] = {};
#pragma unroll 1
  for (int kk = 0; kk < CDIM; kk += 4) {
    float4 wk = *(const float4*)(cn_w + kk);
    float4 bk = *(const float4*)(cn_b + kk);
#pragma unroll
    for (int j = 0; j < 4; ++j) {
      float4 Wr = *(const float4*)(ctx_w + (size_t)(ccol + j) * 768 + kk);
      s1v[j] += Wr.x * wk.x + Wr.y * wk.y + Wr.z * wk.z + Wr.w * wk.w;
      c1v[j] += Wr.x * bk.x + Wr.y * bk.y + Wr.z * bk.z + Wr.w * bk.w;
    }
  }

  // ---- stage bf16(prev_ctx) into g_lds[0]
  {
    float4 c4 = *(const float4*)(prev_ctx + bb * CDIM + ccol);
    ushort4 u; u.x = f2bf(c4.x); u.y = f2bf(c4.y); u.z = f2bf(c4.z); u.w = f2bf(c4.w);
    *(ushort4*)&g_lds[0][bb * 288 + ccol] = u;
  }

  // ---- plain-W fragments for step 0
  uint32x4 wfu[4][8];
#pragma unroll
  for (int mt = 0; mt < 4; ++mt)
#pragma unroll
    for (int kt = 0; kt < 8; ++kt) {
      const float* s = ctx_w + (size_t)(wave * 64 + mt * 16 + l15) * 768 + kt * 32 + lhi * 8;
      float4 f0 = *(const float4*)s, f1 = *(const float4*)(s + 4);
      uint32x4 vw;
      vw.x = pk2(f2bf(f0.x), f2bf(f0.y)); vw.y = pk2(f2bf(f0.z), f2bf(f0.w));
      vw.z = pk2(f2bf(f1.x), f2bf(f1.y)); vw.w = pk2(f2bf(f1.z), f2bf(f1.w));
      wfu[mt][kt] = vw;
    }
  float4 pf = *(const float4*)(P + ((size_t)bb * SEQ + 0) * CDIM + ccol);
  __syncthreads();

  // ---- step 0: raw0 = W @ bf16(prev_ctx); g_0 = gelu(raw0 + P[0])
  float gr[4];
  {
    uint32x4 bfr[8];
#pragma unroll
    for (int kt = 0; kt < 8; ++kt)
      bfr[kt] = *(const uint32x4*)(&g_lds[0][bb * 288 + kt * 32 + lhi * 8]);
    f32x4 acc[4] = {};
#pragma unroll
    for (int mt = 0; mt < 4; ++mt)
#pragma unroll
      for (int kt = 0; kt < 8; ++kt)
        acc[mt] = mfma16(__builtin_bit_cast(bf16x8, wfu[mt][kt]),
                         __builtin_bit_cast(bf16x8, bfr[kt]), acc[mt]);
    f32x4 av = (ss == 0) ? acc[0] : (ss == 1) ? acc[1] : (ss == 2) ? acc[2] : acc[3];
    gr[0] = gelu_f(av[0] + pf.x); gr[1] = gelu_f(av[1] + pf.y);
    gr[2] = gelu_f(av[2] + pf.z); gr[3] = gelu_f(av[3] + pf.w);
  }

  // ---- swap fragments to W' = W_c * diag(cn_w)
#pragma unroll
  for (int mt = 0; mt < 4; ++mt)
#pragma unroll
    for (int kt = 0; kt < 8; ++kt) {
      int k = kt * 32 + lhi * 8;
      const float* s = ctx_w + (size_t)(wave * 64 + mt * 16 + l15) * 768 + k;
      float4 f0 = *(const float4*)s, f1 = *(const float4*)(s + 4);
      float4 w0 = *(const float4*)(cn_w + k), w1 = *(const float4*)(cn_w + k + 4);
      uint32x4 vw;
      vw.x = pk2(f2bf(f0.x * w0.x), f2bf(f0.y * w0.y));
      vw.y = pk2(f2bf(f0.z * w0.z), f2bf(f0.w * w0.w));
      vw.z = pk2(f2bf(f1.x * w1.x), f2bf(f1.y * w1.y));
      vw.w = pk2(f2bf(f1.z * w1.z), f2bf(f1.w * w1.w));
      wfu[mt][kt] = vw;
    }
#pragma unroll
  for (int mt = 0; mt < 4; ++mt)
#pragma unroll
    for (int kt = 0; kt < 8; ++kt)
      asm volatile("" : "+v"(wfu[mt][kt]));

  // ---- P prefetch slots: iter t uses slot (t+1)&3 (=P[t+1]), loads slot t&3 (=P[t+4])
  float4 ps0, ps1, ps2, ps3;
  ps1 = *(const float4*)(P + ((size_t)bb * SEQ + 1) * CDIM + ccol);
  ps2 = *(const float4*)(P + ((size_t)bb * SEQ + 2) * CDIM + ccol);
  ps3 = *(const float4*)(P + ((size_t)bb * SEQ + 3) * CDIM + ccol);
  ps0 = ps3;   // placeholder; overwritten at t=0
  __syncthreads();                         // everyone done reading g_lds[0] staging

  // ---- write g_0 (overwrites staging) + wave partials into buffer 0
  {
    ushort4 u; u.x = f2bf(gr[0]); u.y = f2bf(gr[1]); u.z = f2bf(gr[2]); u.w = f2bf(gr[3]);
    *(ushort4*)&g_lds[0][bb * 288 + ccol] = u;
    float lsm = gr[0] + gr[1] + gr[2] + gr[3];
    float lsq = gr[0]*gr[0] + gr[1]*gr[1] + gr[2]*gr[2] + gr[3]*gr[3];
    lsm += __shfl_xor(lsm, 4);  lsq += __shfl_xor(lsq, 4);
    lsm += __shfl_xor(lsm, 8);  lsq += __shfl_xor(lsq, 8);
    lsm += __shfl_xor(lsm, 16); lsq += __shfl_xor(lsq, 16);
    lsm += __shfl_xor(lsm, 32); lsq += __shfl_xor(lsq, 32);
    if (ss == 0 && lhi == 0) {
      part_lds[0][bb][wave][0] = lsm;
      part_lds[0][bb][wave][1] = lsq;
    }
  }
  __syncthreads();

#define SCAN_STEP(T, CUR, NXT, PUSE, PLOAD)                                          \
  {                                                                                  \
    int tp = ((T) + 4 < SEQ) ? (T) + 4 : SEQ - 1;                                    \
    PLOAD = *(const float4*)(P + ((size_t)bb * SEQ + tp) * CDIM + ccol);             \
    uint32x4 bfr[8];                                                                 \
    _Pragma("unroll")                                                                \
    for (int kt = 0; kt < 8; ++kt)                                                   \
      bfr[kt] = *(const uint32x4*)(&g_lds[CUR][bb * 288 + kt * 32 + lhi * 8]);       \
    const float4* pp = (const float4*)&part_lds[CUR][bb][0][0];                      \
    float4 qpa = pp[0], qpb = pp[1];                                                 \
    f32x4 accA[4] = {}, accB[4] = {};                                                \
    _Pragma("unroll")                                                                \
    for (int mt = 0; mt < 4; ++mt) {                                                 \
      accA[mt] = mfma16(__builtin_bit_cast(bf16x8, wfu[mt][0]), __builtin_bit_cast(bf16x8, bfr[0]), accA[mt]); \
      accB[mt] = mfma16(__builtin_bit_cast(bf16x8, wfu[mt][4]), __builtin_bit_cast(bf16x8, bfr[4]), accB[mt]); \
      accA[mt] = mfma16(__builtin_bit_cast(bf16x8, wfu[mt][1]), __builtin_bit_cast(bf16x8, bfr[1]), accA[mt]); \
      accB[mt] = mfma16(__builtin_bit_cast(bf16x8, wfu[mt][5]), __builtin_bit_cast(bf16x8, bfr[5]), accB[mt]); \
      accA[mt] = mfma16(__builtin_bit_cast(bf16x8, wfu[mt][2]), __builtin_bit_cast(bf16x8, bfr[2]), accA[mt]); \
      accB[mt] = mfma16(__builtin_bit_cast(bf16x8, wfu[mt][6]), __builtin_bit_cast(bf16x8, bfr[6]), accB[mt]); \
      accA[mt] = mfma16(__builtin_bit_cast(bf16x8, wfu[mt][3]), __builtin_bit_cast(bf16x8, bfr[3]), accA[mt]); \
      accB[mt] = mfma16(__builtin_bit_cast(bf16x8, wfu[mt][7]), __builtin_bit_cast(bf16x8, bfr[7]), accB[mt]); \
    }                                                                                \
    float sm = (qpa.x + qpa.z) + (qpb.x + qpb.z);                                    \
    float sq = (qpa.y + qpa.w) + (qpb.y + qpb.w);                                    \
    float mu  = sm * (1.f / CDIM);                                                   \
    float inv = rsqrtf(sq * (1.f / CDIM) - mu * mu + 1e-5f);                         \
    float invmu = inv * mu;                                                          \
    float4 y;                                                                        \
    y.x = wv.x * (inv * gr[0] - invmu) + bvv.x;                                      \
    y.y = wv.y * (inv * gr[1] - invmu) + bvv.y;                                      \
    y.z = wv.z * (inv * gr[2] - invmu) + bvv.z;                                      \
    y.w = wv.w * (inv * gr[3] - invmu) + bvv.w;                                      \
    *(float4*)(x + ((size_t)bb * SEQ + (T)) * CDIM + ccol) = y;                      \
    f32x4 avA = (ss == 0) ? accA[0] : (ss == 1) ? accA[1] : (ss == 2) ? accA[2] : accA[3]; \
    f32x4 avB = (ss == 0) ? accB[0] : (ss == 1) ? accB[1] : (ss == 2) ? accB[2] : accB[3]; \
    f32x4 av = avA + avB;                                                            \
    gr[0] = gelu_f(inv * av[0] - invmu * s1v[0] + c1v[0] + PUSE.x);                  \
    gr[1] = gelu_f(inv * av[1] - invmu * s1v[1] + c1v[1] + PUSE.y);                  \
    gr[2] = gelu_f(inv * av[2] - invmu * s1v[2] + c1v[2] + PUSE.z);                  \
    gr[3] = gelu_f(inv * av[3] - invmu * s1v[3] + c1v[3] + PUSE.w);                  \
    {                                                                                \
      ushort4 u; u.x = f2bf(gr[0]); u.y = f2bf(gr[1]); u.z = f2bf(gr[2]); u.w = f2bf(gr[3]); \
      *(ushort4*)&g_lds[NXT][bb * 288 + ccol] = u;                                   \
    }                                                                                \
    float lsm = gr[0] + gr[1] + gr[2] + gr[3];                                       \
    float lsq = gr[0]*gr[0] + gr[1]*gr[1] + gr[2]*gr[2] + gr[3]*gr[3];               \
    lsm += __shfl_xor(lsm, 4);  lsq += __shfl_xor(lsq, 4);                           \
    lsm += __shfl_xor(lsm, 8);  lsq += __shfl_xor(lsq, 8);                           \
    lsm += __shfl_xor(lsm, 16); lsq += __shfl_xor(lsq, 16);                          \
    lsm += __shfl_xor(lsm, 32); lsq += __shfl_xor(lsq, 32);                          \
    if (ss == 0 && lhi == 0) {                                                       \
      part_lds[NXT][bb][wave][0] = lsm;                                              \
      part_lds[NXT][bb][wave][1] = lsq;                                              \
    }                                                                                \
    asm volatile("s_waitcnt lgkmcnt(0)" ::: "memory");                               \
    __builtin_amdgcn_s_barrier();                                                    \
    __builtin_amdgcn_sched_barrier(0);                                               \
  }

  for (int t = 0; t < SEQ; t += 4) {
    SCAN_STEP(t,     0, 1, ps1, ps0)
    SCAN_STEP(t + 1, 1, 0, ps2, ps1)
    SCAN_STEP(t + 2, 0, 1, ps3, ps2)
    SCAN_STEP(t + 3, 1, 0, ps0, ps3)
  }
#undef SCAN_STEP
}

// ---------------------------------------------------------------- causal flash attention, D=32, MFMA
// No online max (|scores| << 80), deferred denominator reduce, 4 K-tiles
// (64 keys) per iteration for ILP. Balanced qtile = bx + 16*wave.
__global__ __launch_bounds__(256) void attn_k(const ushort* __restrict__ Q,
                                              const ushort* __restrict__ K,
                                              const ushort* __restrict__ VT,
                                              ushort* __restrict__ O) {
  __shared__ __attribute__((aligned(16))) ushort Plds[4 * 16 * 64];  // per-wave 16x64 P tile
  const int tid = threadIdx.x, lane = tid & 63, wave = tid >> 6;
  const int bh = blockIdx.y;
  const int qtile = blockIdx.x + 16 * wave;
  const int q0 = qtile * 16;
  const int l15 = lane & 15, lhi = lane >> 4;
  const float scale = 0.17677669529663689f;   // 1/sqrt(32)

  bf16x8 qa = __builtin_bit_cast(bf16x8,
      *(const uint4*)(Q + ((size_t)bh * SEQ + q0 + l15) * HDIM + lhi * 8));
  const ushort* Kb = K + (size_t)bh * SEQ * HDIM;
  const ushort* Vb = VT + (size_t)bh * HDIM * SEQ;
  ushort* Pw = &Plds[wave * 1024];

  f32x4 o0 = {}, o1 = {};
  float lacc[4] = {};

  for (int kt = 0; kt <= qtile; kt += 4) {
    f32x4 s[4];
    f32x4 z = {};
#pragma unroll
    for (int j = 0; j < 4; ++j) {
      bf16x8 kf = __builtin_bit_cast(bf16x8,
          *(const uint4*)(Kb + (size_t)((kt + j) * 16 + l15) * HDIM + lhi * 8));
      s[j] = mfma16(qa, kf, z);
    }
    float p[4][4];
#pragma unroll
    for (int j = 0; j < 4; ++j) {
      const bool tv = (kt + j <= qtile);
#pragma unroll
      for (int r = 0; r < 4; ++r) {
        int qr = q0 + lhi * 4 + r;
        int kc = (kt + j) * 16 + l15;
        p[j][r] = (tv && kc <= qr) ? __expf(s[j][r] * scale) : 0.f;
        lacc[r] += p[j][r];
      }
    }
#pragma unroll
    for (int j = 0; j < 4; ++j)
#pragma unroll
      for (int r = 0; r < 4; ++r)
        Pw[(lhi * 4 + r) * 64 + j * 16 + l15] = f2bf(p[j][r]);
#pragma unroll
    for (int w = 0; w < 2; ++w) {
      bf16x8 pa  = __builtin_bit_cast(bf16x8, *(const uint4*)(&Pw[l15 * 64 + w * 32 + lhi * 8]));
      bf16x8 v0f = __builtin_bit_cast(bf16x8,
          *(const uint4*)(Vb + (size_t)l15 * SEQ + kt * 16 + w * 32 + lhi * 8));
      bf16x8 v1f = __builtin_bit_cast(bf16x8,
          *(const uint4*)(Vb + (size_t)(16 + l15) * SEQ + kt * 16 + w * 32 + lhi * 8));
      o0 = mfma16(pa, v0f, o0);
      o1 = mfma16(pa, v1f, o1);
    }
  }
#pragma unroll
  for (int msk = 1; msk <= 8; msk <<= 1)
#pragma unroll
    for (int r = 0; r < 4; ++r) lacc[r] += __shfl_xor(lacc[r], msk);

  const int b = bh >> 3, h = bh & 7;
#pragma unroll
  for (int r = 0; r < 4; ++r) {
    float inv = 1.f / lacc[r];
    int qr = q0 + lhi * 4 + r;
    size_t base = ((size_t)(b * SEQ + qr)) * CDIM + h * HDIM;
    O[base + l15]      = f2bf(o0[r] * inv);
    O[base + 16 + l15] = f2bf(o1[r] * inv);
  }
}

// ---------------------------------------------------------------- launcher
static size_t ws_take(size_t& o, size_t bytes) {
  size_t r = o;
  o += (bytes + 255) & ~(size_t)255;
  return r;
}

extern "C" void kernel_launch(void* const* d_in, const int* in_sizes, int n_in,
                              void* d_out, int out_size, void* d_ws, size_t ws_size,
                              hipStream_t stream) {
  (void)in_sizes; (void)n_in; (void)out_size; (void)ws_size;
  const int*   input_ids = (const int*)  d_in[0];
  const float* prev_ctx  = (const float*)d_in[1];
  const float* embed_w   = (const float*)d_in[2];
  const float* en_w      = (const float*)d_in[3];
  const float* en_b      = (const float*)d_in[4];
  const float* ctx_w     = (const float*)d_in[5];
  const float* ctx_b     = (const float*)d_in[6];
  const float* cn_w      = (const float*)d_in[7];
  const float* cn_b      = (const float*)d_in[8];
  const float* ln1_w     = (const float*)d_in[9];
  const float* ln1_b     = (const float*)d_in[10];
  const float* ln2_w     = (const float*)d_in[11];
  const float* ln2_b     = (const float*)d_in[12];
  const float* qkv_w     = (const float*)d_in[13];
  const float* qkv_b     = (const float*)d_in[14];
  const float* ao_w      = (const float*)d_in[15];
  const float* ao_b      = (const float*)d_in[16];
  const float* fc1_w     = (const float*)d_in[17];
  const float* fc1_b     = (const float*)d_in[18];
  const float* fc2_w     = (const float*)d_in[19];
  const float* fc2_b     = (const float*)d_in[20];
  const float* fln_w     = (const float*)d_in[21];
  const float* fln_b     = (const float*)d_in[22];
  const float* out_w     = (const float*)d_in[23];
  float* logits = (float*)d_out;

  char* ws = (char*)d_ws;
  size_t o = 0;
  ushort* WB_OUT = (ushort*)(ws + ws_take(o, (size_t)NVOC * CDIM * 2));
  ushort* WQKV   = (ushort*)(ws + ws_take(o, (size_t)NLAY * 768 * CDIM * 2));
  ushort* WAO    = (ushort*)(ws + ws_take(o, (size_t)NLAY * CDIM * CDIM * 2));
  ushort* WFC1   = (ushort*)(ws + ws_take(o, (size_t)NLAY * IDIM * CDIM * 2));
  ushort* WFC2   = (ushort*)(ws + ws_take(o, (size_t)NLAY * CDIM * IDIM * 2));
  ushort* TOK    = (ushort*)(ws + ws_take(o, (size_t)NROWS * EDIM * 2));
  float*  PBUF   = (float*) (ws + ws_take(o, (size_t)NROWS * CDIM * 4));
  float*  XBUF   = (float*) (ws + ws_take(o, (size_t)NROWS * CDIM * 4));
  ushort* AIN    = (ushort*)(ws + ws_take(o, (size_t)NROWS * CDIM * 2));
  ushort* MIN    = (ushort*)(ws + ws_take(o, (size_t)NROWS * CDIM * 2));
  ushort* QB     = (ushort*)(ws + ws_take(o, (size_t)NROWS * CDIM * 2));
  ushort* KB     = (ushort*)(ws + ws_take(o, (size_t)NROWS * CDIM * 2));
  ushort* VTB    = (ushort*)(ws + ws_take(o, (size_t)NROWS * CDIM * 2));
  ushort* OB     = (ushort*)(ws + ws_take(o, (size_t)NROWS * CDIM * 2));
  ushort* TBUF   = (ushort*)(ws + ws_take(o, (size_t)NROWS * IDIM * 2));
  ushort* XLN    = (ushort*)(ws + ws_take(o, (size_t)NROWS * CDIM * 2));

  embed_ln_k<<<dim3(NROWS), dim3(64), 0, stream>>>(input_ids, embed_w, en_w, en_b, TOK);
  gemm64_k<GF_BIAS | GF_WF32><<<dim3(64, 4), dim3(256), 0, stream>>>(
      TOK, EDIM, (const void*)(ctx_w + 256), 768, ctx_b, (void*)PBUF, CDIM, EDIM);
  // block 0: sequential scan; blocks 1..256: all fp32->bf16 weight conversion (free)
  scan_fused_k<<<dim3(257), dim3(256), 0, stream>>>(
      ctx_w, prev_ctx, PBUF, cn_w, cn_b, XBUF,
      qkv_w, ao_w, fc1_w, fc2_w, out_w, WQKV, WAO, WFC1, WFC2, WB_OUT);

  for (int l = 0; l < NLAY; ++l) {
    ln_k<true><<<dim3(NROWS / 4), dim3(256), 0, stream>>>(
        XBUF, ln1_w + l * CDIM, ln1_b + l * CDIM, ln2_w + l * CDIM, ln2_b + l * CDIM, AIN, MIN);
    qkvrope_k<<<dim3(64, 12), dim3(256), 0, stream>>>(
        AIN, WQKV + (size_t)l * 768 * CDIM, qkv_b + l * 768, QB, KB, VTB);
    attn_k<<<dim3(16, 32), dim3(256), 0, stream>>>(QB, KB, VTB, OB);
    gemm64_k<GF_BIAS | GF_GELU | GF_BF16O><<<dim3(64, 16), dim3(256), 0, stream>>>(
        MIN, CDIM, (const void*)(WFC1 + (size_t)l * IDIM * CDIM), CDIM,
        fc1_b + l * IDIM, (void*)TBUF, IDIM, CDIM);
    gemm64_dual_k<<<dim3(64, 4), dim3(256), 0, stream>>>(
        OB, CDIM, WAO + (size_t)l * CDIM * CDIM, CDIM, CDIM,
        TBUF, IDIM, WFC2 + (size_t)l * CDIM * IDIM, IDIM, IDIM,
        ao_b + l * CDIM, fc2_b + l * CDIM, XBUF, CDIM);
  }

  ln_k<false><<<dim3(NROWS / 4), dim3(256), 0, stream>>>(
      XBUF, fln_w, fln_b, nullptr, nullptr, XLN, nullptr);
  gemm_k<0><<<dim3(32, 393), dim3(256), 0, stream>>>(
      XLN, CDIM, (const void*)WB_OUT, CDIM, nullptr, (void*)logits, NVOC, CDIM);
}